// Round 1
// baseline (358.255 us; speedup 1.0000x reference)
//
#include <hip/hip_runtime.h>
#include <math.h>

#define BATCH   256
#define NBLK    5000
#define NBLKP   5024      // padded row stride (multiple of 32)
#define IN_DIM  400000
#define D1      1024
#define D2      256

// ---------------------------------------------------------------------------
// Stage 1: sparse block dot products.
// g[b][j] = dot(x[b, 80j:80j+80], sv[80j:80j+80]).  4 lanes per block j.
// Also zeroes the pad columns [5000,5024) so GEMM1 needs no A-guard.
// ---------------------------------------------------------------------------
__global__ __launch_bounds__(256) void k_sparse(const float* __restrict__ x,
                                                const float* __restrict__ sv,
                                                float* __restrict__ g) {
    const int b   = blockIdx.y;
    const int tid = threadIdx.x;
    const int jj  = tid >> 2;          // block-in-tile 0..63
    const int s   = tid & 3;           // sub-lane 0..3
    const int j   = blockIdx.x * 64 + jj;
    if (j >= NBLK) {
        if (j < NBLKP && s == 0) g[(size_t)b * NBLKP + j] = 0.0f;
        return;
    }
    const float4* xr = reinterpret_cast<const float4*>(x + (size_t)b * IN_DIM + (size_t)j * 80);
    const float4* sr = reinterpret_cast<const float4*>(sv + (size_t)j * 80);
    float acc = 0.0f;
#pragma unroll
    for (int r = 0; r < 5; ++r) {
        float4 xv = xr[r * 4 + s];
        float4 sg = sr[r * 4 + s];
        acc += xv.x * sg.x + xv.y * sg.y + xv.z * sg.z + xv.w * sg.w;
    }
    acc += __shfl_xor(acc, 1);
    acc += __shfl_xor(acc, 2);
    if (s == 0) g[(size_t)b * NBLKP + j] = acc;
}

// ---------------------------------------------------------------------------
// Stage 2: LayerNorm over the 5000 blocks of each row, in place.
// ---------------------------------------------------------------------------
__global__ __launch_bounds__(256) void k_ln(float* __restrict__ g,
                                            const float* __restrict__ gamma,
                                            const float* __restrict__ beta) {
    const int b   = blockIdx.x;
    const int tid = threadIdx.x;
    float* row = g + (size_t)b * NBLKP;
    float s = 0.0f, ss = 0.0f;
    for (int j = tid; j < NBLK; j += 256) {
        float v = row[j];
        s += v; ss += v * v;
    }
#pragma unroll
    for (int o = 32; o > 0; o >>= 1) {
        s  += __shfl_xor(s, o);
        ss += __shfl_xor(ss, o);
    }
    __shared__ float ls[4], lss[4];
    const int wid = tid >> 6;
    if ((tid & 63) == 0) { ls[wid] = s; lss[wid] = ss; }
    __syncthreads();
    s  = ls[0] + ls[1] + ls[2] + ls[3];
    ss = lss[0] + lss[1] + lss[2] + lss[3];
    const float mu  = s / (float)NBLK;
    const float var = ss / (float)NBLK - mu * mu;
    const float rs  = rsqrtf(var + 1e-5f);
    for (int j = tid; j < NBLK; j += 256) {
        float v = row[j];
        row[j] = (v - mu) * rs * gamma[j] + beta[j];
    }
}

// ---------------------------------------------------------------------------
// fp32 tiled GEMM: C[m][n] = dot(A[m][0:K], W[n][0:K]) + bias[n]  (opt sigmoid)
// A has padded row stride KPAD with zeros beyond K. W is [N][K] exact
// (GUARD_K guards the last K-chunk against OOB reads of W).
// 32x32 tile, 256 threads, 2x2 per thread, transposed LDS (+2 pad).
// ---------------------------------------------------------------------------
template <int K, int KPAD, int LDC, bool GUARD_K, bool SIGMOID>
__global__ __launch_bounds__(256) void k_gemm(const float* __restrict__ A,
                                              const float* __restrict__ W,
                                              const float* __restrict__ bias,
                                              float* __restrict__ C) {
    const int m0  = blockIdx.y * 32;
    const int n0  = blockIdx.x * 32;
    const int tid = threadIdx.x;
    __shared__ float As[32][34];   // [k][m]
    __shared__ float Ws[32][34];   // [k][n]
    const int lr = tid >> 3;       // 0..31 (row within tile)
    const int lc = tid & 7;        // 0..7  (float4 column)
    const int ty = tid >> 4;       // 0..15 -> m pair
    const int tx = tid & 15;       // 0..15 -> n pair
    float acc00 = 0.f, acc01 = 0.f, acc10 = 0.f, acc11 = 0.f;

    for (int k0 = 0; k0 < KPAD; k0 += 32) {
        {   // A chunk (always in-bounds: A padded with zeros to KPAD)
            const float* src = A + (size_t)(m0 + lr) * KPAD + k0 + lc * 4;
            float4 v = *reinterpret_cast<const float4*>(src);
            As[lc * 4 + 0][lr] = v.x;
            As[lc * 4 + 1][lr] = v.y;
            As[lc * 4 + 2][lr] = v.z;
            As[lc * 4 + 3][lr] = v.w;
        }
        {   // W chunk
            const size_t base = (size_t)(n0 + lr) * K + k0 + lc * 4;
            float4 v;
            if (!GUARD_K || (k0 + 32 <= K)) {
                v = *reinterpret_cast<const float4*>(W + base);
            } else {
                v.x = (k0 + lc * 4 + 0 < K) ? W[base + 0] : 0.f;
                v.y = (k0 + lc * 4 + 1 < K) ? W[base + 1] : 0.f;
                v.z = (k0 + lc * 4 + 2 < K) ? W[base + 2] : 0.f;
                v.w = (k0 + lc * 4 + 3 < K) ? W[base + 3] : 0.f;
            }
            Ws[lc * 4 + 0][lr] = v.x;
            Ws[lc * 4 + 1][lr] = v.y;
            Ws[lc * 4 + 2][lr] = v.z;
            Ws[lc * 4 + 3][lr] = v.w;
        }
        __syncthreads();
#pragma unroll
        for (int k = 0; k < 32; ++k) {
            float2 a = *reinterpret_cast<const float2*>(&As[k][ty * 2]);
            float2 w = *reinterpret_cast<const float2*>(&Ws[k][tx * 2]);
            acc00 += a.x * w.x; acc01 += a.x * w.y;
            acc10 += a.y * w.x; acc11 += a.y * w.y;
        }
        __syncthreads();
    }

    const int m = m0 + ty * 2;
    const int n = n0 + tx * 2;
    const float bx = bias[n], by = bias[n + 1];
    float v00 = acc00 + bx, v01 = acc01 + by;
    float v10 = acc10 + bx, v11 = acc11 + by;
    if (SIGMOID) {
        v00 = 1.0f / (1.0f + expf(-v00));
        v01 = 1.0f / (1.0f + expf(-v01));
        v10 = 1.0f / (1.0f + expf(-v10));
        v11 = 1.0f / (1.0f + expf(-v11));
    }
    float2 r0 = {v00, v01};
    float2 r1 = {v10, v11};
    *reinterpret_cast<float2*>(&C[(size_t)m * LDC + n])       = r0;
    *reinterpret_cast<float2*>(&C[(size_t)(m + 1) * LDC + n]) = r1;
}

// ---------------------------------------------------------------------------
// Stage 5: out[b] = dot(sig[b, 0:256], W3) + b3.  One wave per row.
// ---------------------------------------------------------------------------
__global__ __launch_bounds__(64) void k_out(const float* __restrict__ h2,
                                            const float* __restrict__ W3,
                                            const float* __restrict__ b3,
                                            float* __restrict__ out) {
    const int b = blockIdx.x;
    const int l = threadIdx.x;
    float acc = 0.0f;
#pragma unroll
    for (int o = 0; o < D2; o += 64) acc += h2[(size_t)b * D2 + o + l] * W3[o + l];
#pragma unroll
    for (int o = 32; o > 0; o >>= 1) acc += __shfl_xor(acc, o);
    if (l == 0) out[b] = acc + b3[0];
}

extern "C" void kernel_launch(void* const* d_in, const int* in_sizes, int n_in,
                              void* d_out, int out_size, void* d_ws, size_t ws_size,
                              hipStream_t stream) {
    const float* x     = (const float*)d_in[0];
    const float* sv    = (const float*)d_in[1];
    const float* gamma = (const float*)d_in[2];
    const float* beta  = (const float*)d_in[3];
    const float* W1    = (const float*)d_in[4];
    const float* b1    = (const float*)d_in[5];
    const float* W2    = (const float*)d_in[6];
    const float* b2    = (const float*)d_in[7];
    const float* W3    = (const float*)d_in[8];
    const float* b3    = (const float*)d_in[9];
    float* out = (float*)d_out;

    char* ws = (char*)d_ws;
    float* g    = (float*)ws;                                   // [256][5024]
    float* out1 = (float*)(ws + (size_t)BATCH * NBLKP * 4);     // [256][1024]
    float* out2 = out1 + (size_t)BATCH * D1;                    // [256][256]

    k_sparse<<<dim3((NBLKP + 63) / 64 + 1, BATCH), 256, 0, stream>>>(x, sv, g);
    k_ln<<<dim3(BATCH), 256, 0, stream>>>(g, gamma, beta);
    k_gemm<NBLK, NBLKP, D1, true, false>
        <<<dim3(D1 / 32, BATCH / 32), 256, 0, stream>>>(g, W1, b1, out1);
    k_gemm<D1, D1, D2, false, true>
        <<<dim3(D2 / 32, BATCH / 32), 256, 0, stream>>>(out1, W2, b2, out2);
    k_out<<<dim3(BATCH), 64, 0, stream>>>(out2, W3, b3, out);
}

// Round 2
// 174.197 us; speedup vs baseline: 2.0566x; 2.0566x over previous
//
#include <hip/hip_runtime.h>
#include <math.h>

#define BATCH   256
#define NBLK    5000
#define NBLKP   5024      // padded row stride for g (fp32 stage-1 output)
#define IN_DIM  400000
#define D1      1024
#define D2      256
#define K1P     5120      // K for GEMM1, padded to multiple of 64
#define NSPLIT  4
#define KSPLIT  (K1P / NSPLIT)   // 1280 -> 20 BK=64 steps per split

typedef __attribute__((ext_vector_type(8))) short short8_t;
typedef __attribute__((ext_vector_type(4))) float f32x4;

static __device__ __forceinline__ unsigned short f2bf(float f) {
    union { float f; unsigned int u; } v; v.f = f;
    unsigned int u = v.u;
    return (unsigned short)((u + 0x7FFFu + ((u >> 16) & 1u)) >> 16);   // RNE
}

// ---------------------------------------------------------------------------
// Stage 1: sparse block dot products (x read once, HBM-bound).
// g[b][j] = dot(x[b, 80j:80j+80], sv[80j:80j+80]).  4 lanes per block j.
// ---------------------------------------------------------------------------
__global__ __launch_bounds__(256) void k_sparse(const float* __restrict__ x,
                                                const float* __restrict__ sv,
                                                float* __restrict__ g) {
    const int b   = blockIdx.y;
    const int tid = threadIdx.x;
    const int jj  = tid >> 2;
    const int s   = tid & 3;
    const int j   = blockIdx.x * 64 + jj;
    if (j >= NBLK) {
        if (j < NBLKP && s == 0) g[(size_t)b * NBLKP + j] = 0.0f;
        return;
    }
    const float4* xr = reinterpret_cast<const float4*>(x + (size_t)b * IN_DIM + (size_t)j * 80);
    const float4* sr = reinterpret_cast<const float4*>(sv + (size_t)j * 80);
    float acc = 0.0f;
#pragma unroll
    for (int r = 0; r < 5; ++r) {
        float4 xv = xr[r * 4 + s];
        float4 sg = sr[r * 4 + s];
        acc += xv.x * sg.x + xv.y * sg.y + xv.z * sg.z + xv.w * sg.w;
    }
    acc += __shfl_xor(acc, 1);
    acc += __shfl_xor(acc, 2);
    if (s == 0) g[(size_t)b * NBLKP + j] = acc;
}

// ---------------------------------------------------------------------------
// Stage 2: LayerNorm over 5000 blocks; writes bf16 A [BATCH][K1P], zero pad.
// ---------------------------------------------------------------------------
__global__ __launch_bounds__(256) void k_ln(const float* __restrict__ g,
                                            const float* __restrict__ gamma,
                                            const float* __restrict__ beta,
                                            unsigned short* __restrict__ A) {
    const int b   = blockIdx.x;
    const int tid = threadIdx.x;
    const float* row = g + (size_t)b * NBLKP;
    float s = 0.0f, ss = 0.0f;
    for (int j = tid; j < NBLK; j += 256) {
        float v = row[j];
        s += v; ss += v * v;
    }
#pragma unroll
    for (int o = 32; o > 0; o >>= 1) {
        s  += __shfl_xor(s, o);
        ss += __shfl_xor(ss, o);
    }
    __shared__ float ls[4], lss[4];
    const int wid = tid >> 6;
    if ((tid & 63) == 0) { ls[wid] = s; lss[wid] = ss; }
    __syncthreads();
    s  = ls[0] + ls[1] + ls[2] + ls[3];
    ss = lss[0] + lss[1] + lss[2] + lss[3];
    const float mu  = s / (float)NBLK;
    const float var = ss / (float)NBLK - mu * mu;
    const float rs  = rsqrtf(var + 1e-5f);
    unsigned short* dst = A + (size_t)b * K1P;
    for (int j = tid; j < K1P; j += 256) {
        float v = (j < NBLK) ? ((row[j] - mu) * rs * gamma[j] + beta[j]) : 0.0f;
        dst[j] = f2bf(v);
    }
}

// ---------------------------------------------------------------------------
// W1 [1024][5000] f32 -> [1024][5120] bf16 (zero pad). One block per row.
// 5000 % 4 == 0 and row stride 20000 B is 16B-aligned -> clean float4 loads.
// ---------------------------------------------------------------------------
__global__ __launch_bounds__(256) void k_convW1(const float* __restrict__ W1,
                                                unsigned short* __restrict__ W1b) {
    const int n = blockIdx.x;
    const float* src = W1 + (size_t)n * NBLK;
    unsigned short* dst = W1b + (size_t)n * K1P;
    for (int c4 = threadIdx.x; c4 < K1P / 4; c4 += 256) {
        const int c = c4 * 4;
        ushort4 o;
        if (c < NBLK) {
            float4 v = *reinterpret_cast<const float4*>(src + c);
            o = { f2bf(v.x), f2bf(v.y), f2bf(v.z), f2bf(v.w) };
        } else {
            o = ushort4{0, 0, 0, 0};
        }
        *reinterpret_cast<ushort4*>(dst + c) = o;
    }
}

// W2 [256][1024] f32 -> bf16. One block per row, one float4 per thread.
__global__ __launch_bounds__(256) void k_convW2(const float* __restrict__ W2,
                                                unsigned short* __restrict__ W2b) {
    const int n = blockIdx.x;
    const int c = threadIdx.x * 4;
    float4 v = *reinterpret_cast<const float4*>(W2 + (size_t)n * D1 + c);
    ushort4 o = { f2bf(v.x), f2bf(v.y), f2bf(v.z), f2bf(v.w) };
    *reinterpret_cast<ushort4*>(W2b + (size_t)n * D1 + c) = o;
}

// ---------------------------------------------------------------------------
// bf16 MFMA GEMM: C[m][n] = sum_k A[m][k] * W[n][k]   (A, W row-major, LDK)
// 64x64 tile, 4 waves (2x2 of 32x32), BK=64, mfma_f32_16x16x32_bf16.
// blockIdx.z = K-split index (partials written to C + z*M*LDC).
// SIG: add bias and apply sigmoid in epilogue (single-split use only).
// ---------------------------------------------------------------------------
template <int LDK, int LDC, bool SIG>
__global__ __launch_bounds__(256) void k_mfma_gemm(const unsigned short* __restrict__ A,
                                                   const unsigned short* __restrict__ W,
                                                   const float* __restrict__ bias,
                                                   float* __restrict__ C,
                                                   int ksteps, int Mtotal) {
    const int m0 = blockIdx.y * 64;
    const int n0 = blockIdx.x * 64;
    const int z  = blockIdx.z;
    const int kbase = z * ksteps * 64;
    float* Cz = C + (size_t)z * (size_t)Mtotal * LDC;

    __shared__ unsigned short As[64][72];   // +8 bf16 pad: 16B-aligned rows, conflict-free b128
    __shared__ unsigned short Ws[64][72];

    const int tid  = threadIdx.x;
    const int wave = tid >> 6;
    const int lane = tid & 63;
    const int wr   = (wave >> 1) * 32;
    const int wc   = (wave & 1) * 32;
    const int lr   = lane & 15;
    const int lk   = (lane >> 4) * 8;
    const int srow = tid >> 3;            // 0..31
    const int scol = (tid & 7) * 8;       // 0..56

    f32x4 acc[2][2] = {};

    for (int t = 0; t < ksteps; ++t) {
        const int k0 = kbase + t * 64;
#pragma unroll
        for (int it = 0; it < 2; ++it) {
            const int r = srow + it * 32;
            *reinterpret_cast<short8_t*>(&As[r][scol]) =
                *reinterpret_cast<const short8_t*>(A + (size_t)(m0 + r) * LDK + k0 + scol);
            *reinterpret_cast<short8_t*>(&Ws[r][scol]) =
                *reinterpret_cast<const short8_t*>(W + (size_t)(n0 + r) * LDK + k0 + scol);
        }
        __syncthreads();
#pragma unroll
        for (int kk = 0; kk < 64; kk += 32) {
            short8_t a0 = *reinterpret_cast<const short8_t*>(&As[wr + lr][kk + lk]);
            short8_t a1 = *reinterpret_cast<const short8_t*>(&As[wr + 16 + lr][kk + lk]);
            short8_t b0 = *reinterpret_cast<const short8_t*>(&Ws[wc + lr][kk + lk]);
            short8_t b1 = *reinterpret_cast<const short8_t*>(&Ws[wc + 16 + lr][kk + lk]);
            acc[0][0] = __builtin_amdgcn_mfma_f32_16x16x32_bf16(a0, b0, acc[0][0], 0, 0, 0);
            acc[0][1] = __builtin_amdgcn_mfma_f32_16x16x32_bf16(a0, b1, acc[0][1], 0, 0, 0);
            acc[1][0] = __builtin_amdgcn_mfma_f32_16x16x32_bf16(a1, b0, acc[1][0], 0, 0, 0);
            acc[1][1] = __builtin_amdgcn_mfma_f32_16x16x32_bf16(a1, b1, acc[1][1], 0, 0, 0);
        }
        __syncthreads();
    }

    const int rbase = (lane >> 4) * 4;
#pragma unroll
    for (int i = 0; i < 2; ++i)
#pragma unroll
        for (int j = 0; j < 2; ++j) {
            const int col = n0 + wc + j * 16 + lr;
            const float bv = SIG ? bias[col] : 0.0f;
#pragma unroll
            for (int r = 0; r < 4; ++r) {
                const int row = m0 + wr + i * 16 + rbase + r;
                float v = acc[i][j][r] + bv;
                if (SIG) v = 1.0f / (1.0f + __expf(-v));
                Cz[(size_t)row * LDC + col] = v;
            }
        }
}

// Sum split-K partials + b1, convert to bf16 A2 [256][1024].
__global__ __launch_bounds__(256) void k_fuse(const float* __restrict__ p,
                                              const float* __restrict__ b1,
                                              unsigned short* __restrict__ A2) {
    const int idx = (blockIdx.x * 256 + threadIdx.x) * 4;       // over 256*1024
    const int col = idx & (D1 - 1);
    const size_t S = (size_t)BATCH * D1;
    float4 s0 = *reinterpret_cast<const float4*>(p + idx);
    float4 s1 = *reinterpret_cast<const float4*>(p + S + idx);
    float4 s2 = *reinterpret_cast<const float4*>(p + 2 * S + idx);
    float4 s3 = *reinterpret_cast<const float4*>(p + 3 * S + idx);
    float4 bb = *reinterpret_cast<const float4*>(b1 + col);
    ushort4 o = { f2bf(s0.x + s1.x + s2.x + s3.x + bb.x),
                  f2bf(s0.y + s1.y + s2.y + s3.y + bb.y),
                  f2bf(s0.z + s1.z + s2.z + s3.z + bb.z),
                  f2bf(s0.w + s1.w + s2.w + s3.w + bb.w) };
    *reinterpret_cast<ushort4*>(A2 + idx) = o;
}

// Final [256]->[1] dot. One wave per row.
__global__ __launch_bounds__(64) void k_out(const float* __restrict__ h2,
                                            const float* __restrict__ W3,
                                            const float* __restrict__ b3,
                                            float* __restrict__ out) {
    const int b = blockIdx.x;
    const int l = threadIdx.x;
    float acc = 0.0f;
#pragma unroll
    for (int o = 0; o < D2; o += 64) acc += h2[(size_t)b * D2 + o + l] * W3[o + l];
#pragma unroll
    for (int o = 32; o > 0; o >>= 1) acc += __shfl_xor(acc, o);
    if (l == 0) out[b] = acc + b3[0];
}

extern "C" void kernel_launch(void* const* d_in, const int* in_sizes, int n_in,
                              void* d_out, int out_size, void* d_ws, size_t ws_size,
                              hipStream_t stream) {
    const float* x     = (const float*)d_in[0];
    const float* sv    = (const float*)d_in[1];
    const float* gamma = (const float*)d_in[2];
    const float* beta  = (const float*)d_in[3];
    const float* W1    = (const float*)d_in[4];
    const float* b1    = (const float*)d_in[5];
    const float* W2    = (const float*)d_in[6];
    const float* b2    = (const float*)d_in[7];
    const float* W3    = (const float*)d_in[8];
    const float* b3    = (const float*)d_in[9];
    float* out = (float*)d_out;

    char* ws = (char*)d_ws;
    size_t off = 0;
    auto alloc = [&](size_t bytes) { char* p = ws + off; off = (off + bytes + 255) & ~(size_t)255; return p; };
    float*          g     = (float*)         alloc((size_t)BATCH * NBLKP * 4);   // 5.1 MB
    unsigned short* Ab    = (unsigned short*)alloc((size_t)BATCH * K1P * 2);     // 2.6 MB
    unsigned short* W1b   = (unsigned short*)alloc((size_t)D1 * K1P * 2);        // 10.5 MB
    float*          out1p = (float*)         alloc((size_t)NSPLIT * BATCH * D1 * 4); // 4.2 MB
    unsigned short* A2b   = (unsigned short*)alloc((size_t)BATCH * D1 * 2);      // 0.5 MB
    unsigned short* W2b   = (unsigned short*)alloc((size_t)D2 * D1 * 2);         // 0.5 MB
    float*          h2    = (float*)         alloc((size_t)BATCH * D2 * 4);      // 0.26 MB

    k_sparse<<<dim3((NBLKP + 63) / 64, BATCH), 256, 0, stream>>>(x, sv, g);
    k_ln<<<dim3(BATCH), 256, 0, stream>>>(g, gamma, beta, Ab);
    k_convW1<<<dim3(D1), 256, 0, stream>>>(W1, W1b);
    k_convW2<<<dim3(D2), 256, 0, stream>>>(W2, W2b);
    k_mfma_gemm<K1P, D1, false>
        <<<dim3(D1 / 64, BATCH / 64, NSPLIT), 256, 0, stream>>>(Ab, W1b, nullptr, out1p, KSPLIT / 64, BATCH);
    k_fuse<<<dim3(BATCH * D1 / (256 * 4)), 256, 0, stream>>>(out1p, b1, A2b);
    k_mfma_gemm<D1, D2, true>
        <<<dim3(D2 / 64, BATCH / 64, 1), 256, 0, stream>>>(A2b, W2b, b2, h2, D1 / 64, BATCH);
    k_out<<<dim3(BATCH), 64, 0, stream>>>(h2, W3, b3, out);
}

// Round 3
// 132.710 us; speedup vs baseline: 2.6995x; 1.3126x over previous
//
#include <hip/hip_runtime.h>
#include <math.h>

#define BATCH   256
#define NBLK    5000
#define NBLKP   5024      // padded row stride for g (fp32 stage-1 output)
#define IN_DIM  400000
#define D1      1024
#define D2      256
#define K1P     5120      // K for GEMM1, padded to multiple of 64
#define NSPLIT  8
#define KSPLIT  (K1P / NSPLIT)   // 640 -> 10 BK=64 steps per split

typedef __attribute__((ext_vector_type(8))) short short8_t;
typedef __attribute__((ext_vector_type(4))) float f32x4;

static __device__ __forceinline__ unsigned short f2bf(float f) {
    union { float f; unsigned int u; } v; v.f = f;
    unsigned int u = v.u;
    return (unsigned short)((u + 0x7FFFu + ((u >> 16) & 1u)) >> 16);   // RNE
}

// ---------------------------------------------------------------------------
// Stage 1: sparse block dot products (x read once, HBM-bound).
// g[b][j] = dot(x[b, 80j:80j+80], sv[80j:80j+80]).  4 lanes per block j.
// ---------------------------------------------------------------------------
__global__ __launch_bounds__(256) void k_sparse(const float* __restrict__ x,
                                                const float* __restrict__ sv,
                                                float* __restrict__ g) {
    const int b   = blockIdx.y;
    const int tid = threadIdx.x;
    const int jj  = tid >> 2;
    const int s   = tid & 3;
    const int j   = blockIdx.x * 64 + jj;
    if (j >= NBLK) {
        if (j < NBLKP && s == 0) g[(size_t)b * NBLKP + j] = 0.0f;
        return;
    }
    const float4* xr = reinterpret_cast<const float4*>(x + (size_t)b * IN_DIM + (size_t)j * 80);
    const float4* sr = reinterpret_cast<const float4*>(sv + (size_t)j * 80);
    float acc = 0.0f;
#pragma unroll
    for (int r = 0; r < 5; ++r) {
        float4 xv = xr[r * 4 + s];
        float4 sg = sr[r * 4 + s];
        acc += xv.x * sg.x + xv.y * sg.y + xv.z * sg.z + xv.w * sg.w;
    }
    acc += __shfl_xor(acc, 1);
    acc += __shfl_xor(acc, 2);
    if (s == 0) g[(size_t)b * NBLKP + j] = acc;
}

// ---------------------------------------------------------------------------
// Stage 2: LayerNorm over 5000 blocks; row cached in registers (20/thread);
// writes bf16 A [BATCH][K1P] with zero pad.
// ---------------------------------------------------------------------------
__global__ __launch_bounds__(256) void k_ln(const float* __restrict__ g,
                                            const float* __restrict__ gamma,
                                            const float* __restrict__ beta,
                                            unsigned short* __restrict__ A) {
    const int b   = blockIdx.x;
    const int tid = threadIdx.x;
    const float* row = g + (size_t)b * NBLKP;
    float v[20];
    float s = 0.0f, ss = 0.0f;
#pragma unroll
    for (int i = 0; i < 20; ++i) {
        const int j = tid + i * 256;
        const float xv = (j < NBLK) ? row[j] : 0.0f;
        v[i] = xv; s += xv; ss += xv * xv;
    }
#pragma unroll
    for (int o = 32; o > 0; o >>= 1) {
        s  += __shfl_xor(s, o);
        ss += __shfl_xor(ss, o);
    }
    __shared__ float ls[4], lss[4];
    const int wid = tid >> 6;
    if ((tid & 63) == 0) { ls[wid] = s; lss[wid] = ss; }
    __syncthreads();
    s  = ls[0] + ls[1] + ls[2] + ls[3];
    ss = lss[0] + lss[1] + lss[2] + lss[3];
    const float mu  = s / (float)NBLK;
    const float var = ss / (float)NBLK - mu * mu;
    const float rs  = rsqrtf(var + 1e-5f);
    unsigned short* dst = A + (size_t)b * K1P;
#pragma unroll
    for (int i = 0; i < 20; ++i) {
        const int j = tid + i * 256;          // max 5119 == K1P-1: covers pad
        const float val = (j < NBLK) ? ((v[i] - mu) * rs * gamma[j] + beta[j]) : 0.0f;
        dst[j] = f2bf(val);
    }
}

// ---------------------------------------------------------------------------
// W1 [1024][5000] f32 -> [1024][5120] bf16 (zero pad), and W2 [256][1024]
// f32 -> bf16, merged into one launch.
// ---------------------------------------------------------------------------
__global__ __launch_bounds__(256) void k_conv(const float* __restrict__ W1,
                                              unsigned short* __restrict__ W1b,
                                              const float* __restrict__ W2,
                                              unsigned short* __restrict__ W2b) {
    const int blk = blockIdx.x;
    if (blk < D1) {
        const float* src = W1 + (size_t)blk * NBLK;
        unsigned short* dst = W1b + (size_t)blk * K1P;
        for (int c4 = threadIdx.x; c4 < K1P / 4; c4 += 256) {
            const int c = c4 * 4;
            ushort4 o;
            if (c < NBLK) {
                float4 v = *reinterpret_cast<const float4*>(src + c);
                o = { f2bf(v.x), f2bf(v.y), f2bf(v.z), f2bf(v.w) };
            } else {
                o = ushort4{0, 0, 0, 0};
            }
            *reinterpret_cast<ushort4*>(dst + c) = o;
        }
    } else {
        const int idx = ((blk - D1) * 256 + threadIdx.x) * 4;   // over D2*D1
        float4 v = *reinterpret_cast<const float4*>(W2 + idx);
        ushort4 o = { f2bf(v.x), f2bf(v.y), f2bf(v.z), f2bf(v.w) };
        *reinterpret_cast<ushort4*>(W2b + idx) = o;
    }
}

// ---------------------------------------------------------------------------
// bf16 MFMA GEMM with reg-staged prefetch: C[m][n] = sum_k A[m][k]*W[n][k].
// 64x64 tile, 4 waves (2x2 of 32x32), BK=64, mfma_f32_16x16x32_bf16.
// Next K-chunk's global loads issue right after the write barrier, so their
// latency hides under ds_read+MFMA of the current chunk.
// blockIdx.z = K-split index (partials at C + z*Mtotal*LDC).
// ---------------------------------------------------------------------------
template <int LDK, int LDC, bool SIG>
__global__ __launch_bounds__(256) void k_mfma_gemm(const unsigned short* __restrict__ A,
                                                   const unsigned short* __restrict__ W,
                                                   const float* __restrict__ bias,
                                                   float* __restrict__ C,
                                                   int ksteps, int Mtotal) {
    const int m0 = blockIdx.y * 64;
    const int n0 = blockIdx.x * 64;
    const int z  = blockIdx.z;
    const int kbase = z * ksteps * 64;
    float* Cz = C + (size_t)z * (size_t)Mtotal * LDC;

    __shared__ unsigned short As[64][72];   // +8 pad: 16B-aligned rows, conflict-free b128
    __shared__ unsigned short Ws[64][72];

    const int tid  = threadIdx.x;
    const int wave = tid >> 6;
    const int lane = tid & 63;
    const int wr   = (wave >> 1) * 32;
    const int wc   = (wave & 1) * 32;
    const int lr   = lane & 15;
    const int lk   = (lane >> 4) * 8;
    const int srow = tid >> 3;            // 0..31
    const int scol = (tid & 7) * 8;       // 0..56

    const unsigned short* Ap = A + (size_t)(m0 + srow) * LDK + kbase + scol;
    const unsigned short* Wp = W + (size_t)(n0 + srow) * LDK + kbase + scol;

    short8_t pa0 = *reinterpret_cast<const short8_t*>(Ap);
    short8_t pa1 = *reinterpret_cast<const short8_t*>(Ap + (size_t)32 * LDK);
    short8_t pw0 = *reinterpret_cast<const short8_t*>(Wp);
    short8_t pw1 = *reinterpret_cast<const short8_t*>(Wp + (size_t)32 * LDK);

    f32x4 acc[2][2] = {};

    for (int t = 0; t < ksteps; ++t) {
        __syncthreads();   // previous chunk fully consumed
        *reinterpret_cast<short8_t*>(&As[srow][scol])      = pa0;
        *reinterpret_cast<short8_t*>(&As[srow + 32][scol]) = pa1;
        *reinterpret_cast<short8_t*>(&Ws[srow][scol])      = pw0;
        *reinterpret_cast<short8_t*>(&Ws[srow + 32][scol]) = pw1;
        __syncthreads();   // chunk visible
        if (t + 1 < ksteps) {
            const unsigned short* An = Ap + (size_t)(t + 1) * 64;
            const unsigned short* Wn = Wp + (size_t)(t + 1) * 64;
            pa0 = *reinterpret_cast<const short8_t*>(An);
            pa1 = *reinterpret_cast<const short8_t*>(An + (size_t)32 * LDK);
            pw0 = *reinterpret_cast<const short8_t*>(Wn);
            pw1 = *reinterpret_cast<const short8_t*>(Wn + (size_t)32 * LDK);
        }
#pragma unroll
        for (int kk = 0; kk < 64; kk += 32) {
            short8_t a0 = *reinterpret_cast<const short8_t*>(&As[wr + lr][kk + lk]);
            short8_t a1 = *reinterpret_cast<const short8_t*>(&As[wr + 16 + lr][kk + lk]);
            short8_t b0 = *reinterpret_cast<const short8_t*>(&Ws[wc + lr][kk + lk]);
            short8_t b1 = *reinterpret_cast<const short8_t*>(&Ws[wc + 16 + lr][kk + lk]);
            acc[0][0] = __builtin_amdgcn_mfma_f32_16x16x32_bf16(a0, b0, acc[0][0], 0, 0, 0);
            acc[0][1] = __builtin_amdgcn_mfma_f32_16x16x32_bf16(a0, b1, acc[0][1], 0, 0, 0);
            acc[1][0] = __builtin_amdgcn_mfma_f32_16x16x32_bf16(a1, b0, acc[1][0], 0, 0, 0);
            acc[1][1] = __builtin_amdgcn_mfma_f32_16x16x32_bf16(a1, b1, acc[1][1], 0, 0, 0);
        }
    }

    const int rbase = (lane >> 4) * 4;
#pragma unroll
    for (int i = 0; i < 2; ++i)
#pragma unroll
        for (int j = 0; j < 2; ++j) {
            const int col = n0 + wc + j * 16 + lr;
            const float bv = SIG ? bias[col] : 0.0f;
#pragma unroll
            for (int r = 0; r < 4; ++r) {
                const int row = m0 + wr + i * 16 + rbase + r;
                float v = acc[i][j][r] + bv;
                if (SIG) v = 1.0f / (1.0f + __expf(-v));
                Cz[(size_t)row * LDC + col] = v;
            }
        }
}

// Sum split-K partials + b1, convert to bf16 A2 [256][1024].
__global__ __launch_bounds__(256) void k_fuse(const float* __restrict__ p,
                                              const float* __restrict__ b1,
                                              unsigned short* __restrict__ A2) {
    const int idx = (blockIdx.x * 256 + threadIdx.x) * 4;       // over 256*1024
    const int col = idx & (D1 - 1);
    const size_t S = (size_t)BATCH * D1;
    float4 bb = *reinterpret_cast<const float4*>(b1 + col);
    float sx = bb.x, sy = bb.y, sz = bb.z, sw = bb.w;
#pragma unroll
    for (int q = 0; q < NSPLIT; ++q) {
        float4 v = *reinterpret_cast<const float4*>(p + q * S + idx);
        sx += v.x; sy += v.y; sz += v.z; sw += v.w;
    }
    ushort4 o = { f2bf(sx), f2bf(sy), f2bf(sz), f2bf(sw) };
    *reinterpret_cast<ushort4*>(A2 + idx) = o;
}

// Final [256]->[1] dot. One wave per row.
__global__ __launch_bounds__(64) void k_out(const float* __restrict__ h2,
                                            const float* __restrict__ W3,
                                            const float* __restrict__ b3,
                                            float* __restrict__ out) {
    const int b = blockIdx.x;
    const int l = threadIdx.x;
    float acc = 0.0f;
#pragma unroll
    for (int o = 0; o < D2; o += 64) acc += h2[(size_t)b * D2 + o + l] * W3[o + l];
#pragma unroll
    for (int o = 32; o > 0; o >>= 1) acc += __shfl_xor(acc, o);
    if (l == 0) out[b] = acc + b3[0];
}

extern "C" void kernel_launch(void* const* d_in, const int* in_sizes, int n_in,
                              void* d_out, int out_size, void* d_ws, size_t ws_size,
                              hipStream_t stream) {
    const float* x     = (const float*)d_in[0];
    const float* sv    = (const float*)d_in[1];
    const float* gamma = (const float*)d_in[2];
    const float* beta  = (const float*)d_in[3];
    const float* W1    = (const float*)d_in[4];
    const float* b1    = (const float*)d_in[5];
    const float* W2    = (const float*)d_in[6];
    const float* b2    = (const float*)d_in[7];
    const float* W3    = (const float*)d_in[8];
    const float* b3    = (const float*)d_in[9];
    float* out = (float*)d_out;

    char* ws = (char*)d_ws;
    size_t off = 0;
    auto alloc = [&](size_t bytes) { char* p = ws + off; off = (off + bytes + 255) & ~(size_t)255; return p; };
    float*          g     = (float*)         alloc((size_t)BATCH * NBLKP * 4);
    unsigned short* Ab    = (unsigned short*)alloc((size_t)BATCH * K1P * 2);
    unsigned short* W1b   = (unsigned short*)alloc((size_t)D1 * K1P * 2);
    float*          out1p = (float*)         alloc((size_t)NSPLIT * BATCH * D1 * 4);
    unsigned short* A2b   = (unsigned short*)alloc((size_t)BATCH * D1 * 2);
    unsigned short* W2b   = (unsigned short*)alloc((size_t)D2 * D1 * 2);
    float*          h2    = (float*)         alloc((size_t)BATCH * D2 * 4);

    k_conv<<<dim3(D1 + D2 * D1 / 1024), 256, 0, stream>>>(W1, W1b, W2, W2b);
    k_sparse<<<dim3((NBLKP + 63) / 64, BATCH), 256, 0, stream>>>(x, sv, g);
    k_ln<<<dim3(BATCH), 256, 0, stream>>>(g, gamma, beta, Ab);
    k_mfma_gemm<K1P, D1, false>
        <<<dim3(D1 / 64, BATCH / 64, NSPLIT), 256, 0, stream>>>(Ab, W1b, nullptr, out1p, KSPLIT / 64, BATCH);
    k_fuse<<<dim3(BATCH * D1 / (256 * 4)), 256, 0, stream>>>(out1p, b1, A2b);
    k_mfma_gemm<D1, D2, true>
        <<<dim3(D2 / 64, BATCH / 64, 1), 256, 0, stream>>>(A2b, W2b, b2, h2, D1 / 64, BATCH);
    k_out<<<dim3(BATCH), 64, 0, stream>>>(h2, W3, b3, out);
}